// Round 7
// baseline (613.892 us; speedup 1.0000x reference)
//
#include <hip/hip_runtime.h>

#define L_SEQ 2048
#define CDIM  1024
#define NH    16
#define HD    64
#define NBH   64       // B*H
#define KDIM  1024

typedef __attribute__((ext_vector_type(4))) float f32x4;
typedef __attribute__((ext_vector_type(8))) short s16x8;
typedef __attribute__((ext_vector_type(4))) short s16x4;

__device__ inline short f2bf(float f) {
  union { float f; unsigned u; } v; v.f = f;
  unsigned r = v.u + 0x7fffu + ((v.u >> 16) & 1u);
  return (short)(r >> 16);
}

__device__ inline f32x4 mfma16(s16x8 a, s16x8 b, f32x4 c) {
  return __builtin_amdgcn_mfma_f32_16x16x32_bf16(a, b, c, 0, 0, 0);
}

// v_cvt_pk_bf16_f32: D[15:0]=bf16(lo), D[31:16]=bf16(hi). No builtin on gfx950 (T12).
__device__ inline unsigned cvt_pk_bf16(float lo, float hi) {
  unsigned r;
  asm("v_cvt_pk_bf16_f32 %0, %1, %2" : "=v"(r) : "v"(lo), "v"(hi));
  return r;
}

// ---------------- fp32 -> bf16 convert (x) ----------------
__global__ __launch_bounds__(256) void convert_f32_bf16(const float* __restrict__ in,
                                                        short* __restrict__ out) {
  int i = (blockIdx.x * 256 + threadIdx.x) * 4;
  typedef __attribute__((ext_vector_type(4))) float fv4;
  fv4 v = *(const fv4*)(in + i);
  s16x4 o;
  o[0] = f2bf(v[0]); o[1] = f2bf(v[1]); o[2] = f2bf(v[2]); o[3] = f2bf(v[3]);
  *(s16x4*)(out + i) = o;
}

// ---------------- W [K=1024][N=3072] fp32 -> Wt [3072][1024] bf16 ----------------
__global__ __launch_bounds__(256) void transpose_w(const float* __restrict__ W,
                                                   short* __restrict__ Wt) {
  __shared__ float tile[64][65];
  int n0 = blockIdx.x * 64, k0 = blockIdx.y * 64;
  int tc = threadIdx.x & 63, tr = threadIdx.x >> 6;
#pragma unroll
  for (int i = 0; i < 16; ++i) {
    int r = i * 4 + tr;
    tile[r][tc] = W[(size_t)(k0 + r) * 3072 + n0 + tc];
  }
  __syncthreads();
#pragma unroll
  for (int i = 0; i < 16; ++i) {
    int r = i * 4 + tr;
    Wt[(size_t)(n0 + r) * 1024 + k0 + tc] = f2bf(tile[tc][r]);
  }
}

// ---------------- V [BH][L][D] bf16 -> Vt [BH][D][L] bf16 ----------------
__global__ __launch_bounds__(256) void transpose_v(const short* __restrict__ V,
                                                   short* __restrict__ Vt) {
  __shared__ short tile[64][72];
  int bh = blockIdx.y, l0 = blockIdx.x * 64;
  const short* Vb = V + (size_t)bh * L_SEQ * HD;
  short* Vtb = Vt + (size_t)bh * HD * L_SEQ;
  int tc = threadIdx.x & 63, tr = threadIdx.x >> 6;
#pragma unroll
  for (int i = 0; i < 16; ++i) {
    int r = i * 4 + tr;
    tile[r][tc] = Vb[(size_t)(l0 + r) * HD + tc];
  }
  __syncthreads();
#pragma unroll
  for (int i = 0; i < 16; ++i) {
    int r = i * 4 + tr;   // d index
    Vtb[(size_t)r * L_SEQ + l0 + tc] = tile[tc][r];
  }
}

// ---------------- QKV GEMM: [8192,1024] x [1024,3072] + bias, scatter to Q/K/V ----------------
#define BKP 40   // padded LDS row stride (shorts)
__global__ __launch_bounds__(256) void qkv_gemm(const short* __restrict__ A,
                                                const short* __restrict__ Bt,
                                                const float* __restrict__ bias,
                                                short* __restrict__ Qo,
                                                short* __restrict__ Ko,
                                                short* __restrict__ Vo) {
  __shared__ __align__(16) short As[128 * BKP];
  __shared__ __align__(16) short Bs[128 * BKP];
  const int t = threadIdx.x;
  const int lane = t & 63, wid = t >> 6;
  const int wm = wid >> 1, wn = wid & 1;
  const int lrow = lane & 15, lg = lane >> 4;
  const int tm = blockIdx.x * 128, tn = blockIdx.y * 128;

  f32x4 acc[4][4];
#pragma unroll
  for (int i = 0; i < 4; ++i)
#pragma unroll
    for (int j = 0; j < 4; ++j) { acc[i][j][0]=0.f; acc[i][j][1]=0.f; acc[i][j][2]=0.f; acc[i][j][3]=0.f; }

  for (int kt = 0; kt < KDIM; kt += 32) {
    __syncthreads();
#pragma unroll
    for (int c = 0; c < 2; ++c) {
      int q = t + 256 * c;              // 0..511 chunk id
      int row = q >> 2, koff = (q & 3) * 8;
      s16x8 av = *(const s16x8*)(A + (size_t)(tm + row) * KDIM + kt + koff);
      *(s16x8*)(As + row * BKP + koff) = av;
      s16x8 bv = *(const s16x8*)(Bt + (size_t)(tn + row) * KDIM + kt + koff);
      *(s16x8*)(Bs + row * BKP + koff) = bv;
    }
    __syncthreads();
    s16x8 af[4], bf[4];
#pragma unroll
    for (int i = 0; i < 4; ++i)
      af[i] = *(const s16x8*)(As + (wm * 64 + i * 16 + lrow) * BKP + lg * 8);
#pragma unroll
    for (int j = 0; j < 4; ++j)
      bf[j] = *(const s16x8*)(Bs + (wn * 64 + j * 16 + lrow) * BKP + lg * 8);
#pragma unroll
    for (int i = 0; i < 4; ++i)
#pragma unroll
      for (int j = 0; j < 4; ++j)
        acc[i][j] = mfma16(af[i], bf[j], acc[i][j]);
  }

  const float QS = 0.125f * 1.4426950408889634f;  // 1/sqrt(D) * log2(e), folded into Q
#pragma unroll
  for (int i = 0; i < 4; ++i)
#pragma unroll
    for (int j = 0; j < 4; ++j) {
      int n = tn + wn * 64 + j * 16 + lrow;
      float bv = bias[n];
      int s = n >> 10, rem = n & 1023;
      int h = rem >> 6, d = rem & 63;
#pragma unroll
      for (int r = 0; r < 4; ++r) {
        int m = tm + wm * 64 + i * 16 + lg * 4 + r;
        int b = m >> 11, l = m & 2047;
        float v = acc[i][j][r] + bv;
        size_t idx = ((size_t)(b * NH + h) * L_SEQ + l) * HD + d;
        if (s == 0)      Qo[idx] = f2bf(v * QS);
        else if (s == 1) Ko[idx] = f2bf(v);
        else             Vo[idx] = f2bf(v);
      }
    }
}

// ---------------- causal flash attention, swapped-QK^T, no-LDS ----------------
// Q,K: [BH][L][D] bf16 (Q pre-scaled by 0.125*log2e), Vt: [BH][D][L] bf16, out fp32 [B][L][C]
// Per wave: 16 q-rows, KVBLK=64. S^T = mfma(K, Q): lane holds q=lane&15, kv=(lane>>4)*4+r.
// Softmax: local max/sum over 16 regs + shfl_xor(16,32). P stays in regs.
// PV B-frag (P^T): dest lane (lrow,lg) needs kv = ks*32 + lg*8 + {0..7} for q=lrow;
//   lane-uniform shfl of both word candidates + dest-side select by lg&2 (round-4 fix).
// Grid: one 64-row q-tile per block, issued longest-first (qt = 31 - blockIdx.x) so the
//   causal work skew load-balances; 2048 blocks x 4 waves = 8192 waves (100% occ cap).
// Defer-max (T13, exact variant): skip fr/rescale when the tile max didn't grow.
__global__ __launch_bounds__(256) void attn(const short* __restrict__ Q,
                                            const short* __restrict__ K,
                                            const short* __restrict__ Vt,
                                            float* __restrict__ out) {
  const int t = threadIdx.x, lane = t & 63, wid = t >> 6;
  const int lrow = lane & 15, lg = lane >> 4;
  const int bh = blockIdx.y;
  const size_t bhoff = (size_t)bh * L_SEQ * HD;
  const short* Qb = Q + bhoff;
  const short* Kb = K + bhoff;
  const short* Vb = Vt + (size_t)bh * HD * L_SEQ;   // [64][2048]
  const int b = bh >> 4, h = bh & 15;
  const int src0 = lrow + ((lane & 16) << 1);       // lrow + 32*(lg&1)
  const int src1 = src0 + 16;
  const bool hi_nf = (lg & 2) != 0;                 // dest-side word select

  const int qt = 31 - (int)blockIdx.x;              // longest-first for load balance
  const int q0 = qt * 64 + wid * 16;
  const int qi = q0 + lrow;

  // Q B-fragment (n=q=lrow, k=d): two 32-d halves
  s16x8 qf0 = *(const s16x8*)(Qb + (size_t)qi * HD + lg * 8);
  s16x8 qf1 = *(const s16x8*)(Qb + (size_t)qi * HD + 32 + lg * 8);

  f32x4 o[4];                         // O^T[d][q]: d = dt*16 + lg*4 + r, q = lrow
#pragma unroll
  for (int dt = 0; dt < 4; ++dt) { o[dt][0]=0.f; o[dt][1]=0.f; o[dt][2]=0.f; o[dt][3]=0.f; }
  float mr = -1e30f, lr = 0.f;

  const int kvend = q0 + 16;
  for (int kv0 = 0; kv0 < kvend; kv0 += 64) {
    // hoist V A-fragments (independent of softmax -> hides L2 latency)
    s16x8 vf[2][4];
#pragma unroll
    for (int ks = 0; ks < 2; ++ks)
#pragma unroll
      for (int dt = 0; dt < 4; ++dt)
        vf[ks][dt] = *(const s16x8*)(Vb + (size_t)(dt * 16 + lrow) * L_SEQ + kv0 + ks * 32 + lg * 8);

    // S^T[kv][q] = K . Q^T   (kv = kv0 + nf*16 + lg*4 + r, q = lrow)
    f32x4 s[4];
#pragma unroll
    for (int nf = 0; nf < 4; ++nf) {
      f32x4 sv; sv[0]=0.f; sv[1]=0.f; sv[2]=0.f; sv[3]=0.f;
      const short* Krow = Kb + (size_t)(kv0 + nf * 16 + lrow) * HD;
      sv = mfma16(*(const s16x8*)(Krow + lg * 8), qf0, sv);
      sv = mfma16(*(const s16x8*)(Krow + 32 + lg * 8), qf1, sv);
      s[nf] = sv;
    }
    // causal mask
    if (kv0 + 63 > q0) {
#pragma unroll
      for (int nf = 0; nf < 4; ++nf)
#pragma unroll
        for (int r = 0; r < 4; ++r)
          if (kv0 + nf * 16 + lg * 4 + r > qi) s[nf][r] = -INFINITY;
    }
    // online softmax for q=lrow: local 16-reg reduce + 2 shfls
    float mt = s[0][0];
#pragma unroll
    for (int nf = 0; nf < 4; ++nf)
#pragma unroll
      for (int r = 0; r < 4; ++r) mt = fmaxf(mt, s[nf][r]);
    mt = fmaxf(mt, __shfl_xor(mt, 16));
    mt = fmaxf(mt, __shfl_xor(mt, 32));
    // defer-max (exact): rescale only if any row's max grew; else fr==1 exactly
    if (__ballot(mt > mr) != 0ull) {
      float mn = fmaxf(mr, mt);
      float fr = exp2f(mr - mn);
      mr = mn;
      lr *= fr;
#pragma unroll
      for (int dt = 0; dt < 4; ++dt) o[dt] *= fr;
    }
    float ps = 0.f;
#pragma unroll
    for (int nf = 0; nf < 4; ++nf)
#pragma unroll
      for (int r = 0; r < 4; ++r) {
        float p = exp2f(s[nf][r] - mr);
        s[nf][r] = p; ps += p;
      }
    ps += __shfl_xor(ps, 16);
    ps += __shfl_xor(ps, 32);
    lr += ps;

    // pack P to bf16 pairs: w0[nf] = (p[0],p[1]), w1[nf] = (p[2],p[3])
    unsigned w0[4], w1[4];
#pragma unroll
    for (int nf = 0; nf < 4; ++nf) {
      w0[nf] = cvt_pk_bf16(s[nf][0], s[nf][1]);
      w1[nf] = cvt_pk_bf16(s[nf][2], s[nf][3]);
    }

    // PV per 32-kv slice: form B-frag of P^T (lane-uniform shfl + dest-side select)
#pragma unroll
    for (int ks = 0; ks < 2; ++ks) {
      int a0 = __shfl((int)w0[2 * ks],     src0);
      int a1 = __shfl((int)w0[2 * ks + 1], src0);
      int b0 = __shfl((int)w1[2 * ks],     src0);
      int b1 = __shfl((int)w1[2 * ks + 1], src0);
      int c0 = __shfl((int)w0[2 * ks],     src1);
      int c1 = __shfl((int)w0[2 * ks + 1], src1);
      int d0 = __shfl((int)w1[2 * ks],     src1);
      int d1 = __shfl((int)w1[2 * ks + 1], src1);
      union { int i[4]; s16x8 v; } pu;
      pu.i[0] = hi_nf ? a1 : a0;
      pu.i[1] = hi_nf ? b1 : b0;
      pu.i[2] = hi_nf ? c1 : c0;
      pu.i[3] = hi_nf ? d1 : d0;
#pragma unroll
      for (int dt = 0; dt < 4; ++dt)
        o[dt] = mfma16(vf[ks][dt], pu.v, o[dt]);
    }
  }

  const float inv = 1.0f / lr;
  const size_t obase = (size_t)(b * L_SEQ + qi) * CDIM + h * HD + lg * 4;
#pragma unroll
  for (int dt = 0; dt < 4; ++dt) {
    f32x4 ov = o[dt] * inv;
    *(f32x4*)(out + obase + dt * 16) = ov;
  }
}

extern "C" void kernel_launch(void* const* d_in, const int* in_sizes, int n_in,
                              void* d_out, int out_size, void* d_ws, size_t ws_size,
                              hipStream_t stream) {
  const float* x    = (const float*)d_in[0];
  const float* W    = (const float*)d_in[1];
  const float* bqkv = (const float*)d_in[2];
  float* out = (float*)d_out;
  char* ws = (char*)d_ws;

  const size_t SZ_XB  = (size_t)8192 * 1024 * 2;   // 16,777,216
  const size_t SZ_WT  = (size_t)3072 * 1024 * 2;   //  6,291,456
  const size_t SZ_HEAD = (size_t)NBH * L_SEQ * HD * 2; // 16,777,216

  short* xb  = (short*)ws;                                  // dead after gemm
  short* wtb = (short*)(ws + SZ_XB);
  short* Qo  = (short*)(ws + SZ_XB + SZ_WT);
  short* Ko  = (short*)(ws + SZ_XB + SZ_WT + SZ_HEAD);
  short* Vo  = (short*)(ws + SZ_XB + SZ_WT + 2 * SZ_HEAD);
  short* Vtb = (short*)ws;                                  // aliases xb (safe: used after gemm)

  convert_f32_bf16<<<8192, 256, 0, stream>>>(x, xb);
  transpose_w<<<dim3(48, 16), 256, 0, stream>>>(W, wtb);
  qkv_gemm<<<dim3(64, 24), 256, 0, stream>>>(xb, wtb, bqkv, Qo, Ko, Vo);
  transpose_v<<<dim3(32, 64), 256, 0, stream>>>(Vo, Vtb);
  attn<<<dim3(32, 64), 256, 0, stream>>>(Qo, Ko, Vtb, out);
}

// Round 8
// 399.964 us; speedup vs baseline: 1.5349x; 1.5349x over previous
//
#include <hip/hip_runtime.h>

#define L_SEQ 2048
#define CDIM  1024
#define NH    16
#define HD    64
#define NBH   64       // B*H
#define KDIM  1024

typedef __attribute__((ext_vector_type(4))) float f32x4;
typedef __attribute__((ext_vector_type(8))) short s16x8;
typedef __attribute__((ext_vector_type(4))) short s16x4;

__device__ inline short f2bf(float f) {
  union { float f; unsigned u; } v; v.f = f;
  unsigned r = v.u + 0x7fffu + ((v.u >> 16) & 1u);
  return (short)(r >> 16);
}

__device__ inline f32x4 mfma16(s16x8 a, s16x8 b, f32x4 c) {
  return __builtin_amdgcn_mfma_f32_16x16x32_bf16(a, b, c, 0, 0, 0);
}

// v_cvt_pk_bf16_f32: D[15:0]=bf16(lo), D[31:16]=bf16(hi). No builtin on gfx950 (T12).
__device__ inline unsigned cvt_pk_bf16(float lo, float hi) {
  unsigned r;
  asm("v_cvt_pk_bf16_f32 %0, %1, %2" : "=v"(r) : "v"(lo), "v"(hi));
  return r;
}

// async global->LDS, 16B/lane. LDS dest is WAVE-UNIFORM base (HW writes lane i at base+i*16);
// global src is per-lane (m104/m173).
__device__ inline void gload_lds16(const short* g, short* l) {
  __builtin_amdgcn_global_load_lds(
      (const __attribute__((address_space(1))) unsigned*)g,
      (__attribute__((address_space(3))) unsigned*)l, 16, 0, 0);
}

// ---------------- fp32 -> bf16 convert (x) ----------------
__global__ __launch_bounds__(256) void convert_f32_bf16(const float* __restrict__ in,
                                                        short* __restrict__ out) {
  int i = (blockIdx.x * 256 + threadIdx.x) * 4;
  typedef __attribute__((ext_vector_type(4))) float fv4;
  fv4 v = *(const fv4*)(in + i);
  s16x4 o;
  o[0] = f2bf(v[0]); o[1] = f2bf(v[1]); o[2] = f2bf(v[2]); o[3] = f2bf(v[3]);
  *(s16x4*)(out + i) = o;
}

// ---------------- W [K=1024][N=3072] fp32 -> Wt [3072][1024] bf16 ----------------
__global__ __launch_bounds__(256) void transpose_w(const float* __restrict__ W,
                                                   short* __restrict__ Wt) {
  __shared__ float tile[64][65];
  int n0 = blockIdx.x * 64, k0 = blockIdx.y * 64;
  int tc = threadIdx.x & 63, tr = threadIdx.x >> 6;
#pragma unroll
  for (int i = 0; i < 16; ++i) {
    int r = i * 4 + tr;
    tile[r][tc] = W[(size_t)(k0 + r) * 3072 + n0 + tc];
  }
  __syncthreads();
#pragma unroll
  for (int i = 0; i < 16; ++i) {
    int r = i * 4 + tr;
    Wt[(size_t)(n0 + r) * 1024 + k0 + tc] = f2bf(tile[tc][r]);
  }
}

// ---------------- V [BH][L][D] bf16 -> Vt [BH][D][L] bf16 ----------------
__global__ __launch_bounds__(256) void transpose_v(const short* __restrict__ V,
                                                   short* __restrict__ Vt) {
  __shared__ short tile[64][72];
  int bh = blockIdx.y, l0 = blockIdx.x * 64;
  const short* Vb = V + (size_t)bh * L_SEQ * HD;
  short* Vtb = Vt + (size_t)bh * HD * L_SEQ;
  int tc = threadIdx.x & 63, tr = threadIdx.x >> 6;
#pragma unroll
  for (int i = 0; i < 16; ++i) {
    int r = i * 4 + tr;
    tile[r][tc] = Vb[(size_t)(l0 + r) * HD + tc];
  }
  __syncthreads();
#pragma unroll
  for (int i = 0; i < 16; ++i) {
    int r = i * 4 + tr;   // d index
    Vtb[(size_t)r * L_SEQ + l0 + tc] = tile[tc][r];
  }
}

// ---------------- QKV GEMM (m97 structure): 128x128 tile, BK=64, global_load_lds + T2 swizzle ----
// LDS layout: As[128][64] bf16 LINEAR (gload_lds requires it). Swizzle is applied on the
// GLOBAL SOURCE (slot c holds global chunk c^(row&7)) and undone on the ds_read addr
// (read chunk g at slot g^(row&7)) — both-sides-or-neither (rule #21). Banks: slot index
// spreads over all 8 16B-slots per 8-row group -> minimal 2-lane/bank aliasing (free).
__global__ __launch_bounds__(256) void qkv_gemm(const short* __restrict__ A,
                                                const short* __restrict__ Bt,
                                                const float* __restrict__ bias,
                                                short* __restrict__ Qo,
                                                short* __restrict__ Ko,
                                                short* __restrict__ Vo) {
  __shared__ __align__(16) short As[128 * 64];
  __shared__ __align__(16) short Bs[128 * 64];
  const int t = threadIdx.x;
  const int lane = t & 63, wid = t >> 6;
  const int wm = wid >> 1, wn = wid & 1;
  const int lrow = lane & 15, lg = lane >> 4;
  const int tm = blockIdx.x * 128, tn = blockIdx.y * 128;

  // staging geometry: per instr, 64 lanes x 16B = 8 rows of 128B. lane l -> row +l>>3, slot l&7.
  const int srow = lane >> 3;                 // 0..7
  const int schunk = (lane & 7) ^ srow;       // pre-swizzled global chunk
  const int sw = lrow & 7;                    // fragment-read swizzle

  f32x4 acc[4][4];
#pragma unroll
  for (int i = 0; i < 4; ++i)
#pragma unroll
    for (int j = 0; j < 4; ++j) { acc[i][j][0]=0.f; acc[i][j][1]=0.f; acc[i][j][2]=0.f; acc[i][j][3]=0.f; }

  for (int kt = 0; kt < KDIM; kt += 64) {
    __syncthreads();                          // prior tile's reads complete
#pragma unroll
    for (int ii = 0; ii < 4; ++ii) {
      int row0 = wid * 32 + ii * 8;           // wave-uniform LDS row base
      int rowg = row0 + srow;
      gload_lds16(A  + (size_t)(tm + rowg) * KDIM + kt + schunk * 8, &As[row0 * 64]);
      gload_lds16(Bt + (size_t)(tn + rowg) * KDIM + kt + schunk * 8, &Bs[row0 * 64]);
    }
    asm volatile("s_waitcnt vmcnt(0)" ::: "memory");
    __syncthreads();                          // all waves' DMA visible

    s16x8 af[4][2], bf[4][2];
#pragma unroll
    for (int i = 0; i < 4; ++i) {
      int row = wm * 64 + i * 16 + lrow;
      af[i][0] = *(const s16x8*)(As + row * 64 + ((lg)     ^ sw) * 8);
      af[i][1] = *(const s16x8*)(As + row * 64 + ((4 + lg) ^ sw) * 8);
    }
#pragma unroll
    for (int j = 0; j < 4; ++j) {
      int row = wn * 64 + j * 16 + lrow;
      bf[j][0] = *(const s16x8*)(Bs + row * 64 + ((lg)     ^ sw) * 8);
      bf[j][1] = *(const s16x8*)(Bs + row * 64 + ((4 + lg) ^ sw) * 8);
    }
#pragma unroll
    for (int i = 0; i < 4; ++i)
#pragma unroll
      for (int j = 0; j < 4; ++j) {
        acc[i][j] = mfma16(af[i][0], bf[j][0], acc[i][j]);
        acc[i][j] = mfma16(af[i][1], bf[j][1], acc[i][j]);
      }
  }

  const float QS = 0.125f * 1.4426950408889634f;  // 1/sqrt(D) * log2(e), folded into Q
#pragma unroll
  for (int i = 0; i < 4; ++i)
#pragma unroll
    for (int j = 0; j < 4; ++j) {
      int n = tn + wn * 64 + j * 16 + lrow;
      float bv = bias[n];
      int s = n >> 10, rem = n & 1023;
      int h = rem >> 6, d = rem & 63;
#pragma unroll
      for (int r = 0; r < 4; ++r) {
        int m = tm + wm * 64 + i * 16 + lg * 4 + r;
        int b = m >> 11, l = m & 2047;
        float v = acc[i][j][r] + bv;
        size_t idx = ((size_t)(b * NH + h) * L_SEQ + l) * HD + d;
        if (s == 0)      Qo[idx] = f2bf(v * QS);
        else if (s == 1) Ko[idx] = f2bf(v);
        else             Vo[idx] = f2bf(v);
      }
    }
}

// ---------------- causal flash attention, swapped-QK^T, no-LDS (round-5 verbatim) ----------------
// Q,K: [BH][L][D] bf16 (Q pre-scaled by 0.125*log2e), Vt: [BH][D][L] bf16, out fp32 [B][L][C]
// Per wave: 16 q-rows, KVBLK=64. S^T = mfma(K, Q): lane holds q=lane&15, kv=(lane>>4)*4+r.
// Block does q-tile pair (qb, 31-qb): EQUAL work per block (33 tiles) — flat occupancy
// beats decaying occupancy (round-7 lesson: grid==capacity means no backfill).
__global__ __launch_bounds__(256) void attn(const short* __restrict__ Q,
                                            const short* __restrict__ K,
                                            const short* __restrict__ Vt,
                                            float* __restrict__ out) {
  const int t = threadIdx.x, lane = t & 63, wid = t >> 6;
  const int lrow = lane & 15, lg = lane >> 4;
  const int bh = blockIdx.y;
  const size_t bhoff = (size_t)bh * L_SEQ * HD;
  const short* Qb = Q + bhoff;
  const short* Kb = K + bhoff;
  const short* Vb = Vt + (size_t)bh * HD * L_SEQ;   // [64][2048]
  const int b = bh >> 4, h = bh & 15;
  const int src0 = lrow + ((lane & 16) << 1);       // lrow + 32*(lg&1)
  const int src1 = src0 + 16;
  const bool hi_nf = (lg & 2) != 0;                 // dest-side word select

#pragma unroll
  for (int tt = 0; tt < 2; ++tt) {
    const int qt = tt ? (31 - (int)blockIdx.x) : (int)blockIdx.x;
    const int q0 = qt * 64 + wid * 16;
    const int qi = q0 + lrow;

    s16x8 qf0 = *(const s16x8*)(Qb + (size_t)qi * HD + lg * 8);
    s16x8 qf1 = *(const s16x8*)(Qb + (size_t)qi * HD + 32 + lg * 8);

    f32x4 o[4];                         // O^T[d][q]: d = dt*16 + lg*4 + r, q = lrow
#pragma unroll
    for (int dt = 0; dt < 4; ++dt) { o[dt][0]=0.f; o[dt][1]=0.f; o[dt][2]=0.f; o[dt][3]=0.f; }
    float mr = -1e30f, lr = 0.f;

    const int kvend = q0 + 16;
    for (int kv0 = 0; kv0 < kvend; kv0 += 64) {
      // hoist V A-fragments (independent of softmax -> hides L2 latency)
      s16x8 vf[2][4];
#pragma unroll
      for (int ks = 0; ks < 2; ++ks)
#pragma unroll
        for (int dt = 0; dt < 4; ++dt)
          vf[ks][dt] = *(const s16x8*)(Vb + (size_t)(dt * 16 + lrow) * L_SEQ + kv0 + ks * 32 + lg * 8);

      // S^T[kv][q] = K . Q^T   (kv = kv0 + nf*16 + lg*4 + r, q = lrow)
      f32x4 s[4];
#pragma unroll
      for (int nf = 0; nf < 4; ++nf) {
        f32x4 sv; sv[0]=0.f; sv[1]=0.f; sv[2]=0.f; sv[3]=0.f;
        const short* Krow = Kb + (size_t)(kv0 + nf * 16 + lrow) * HD;
        sv = mfma16(*(const s16x8*)(Krow + lg * 8), qf0, sv);
        sv = mfma16(*(const s16x8*)(Krow + 32 + lg * 8), qf1, sv);
        s[nf] = sv;
      }
      // causal mask
      if (kv0 + 63 > q0) {
#pragma unroll
        for (int nf = 0; nf < 4; ++nf)
#pragma unroll
          for (int r = 0; r < 4; ++r)
            if (kv0 + nf * 16 + lg * 4 + r > qi) s[nf][r] = -INFINITY;
      }
      // online softmax for q=lrow: local 16-reg reduce + 2 shfls
      float mt = s[0][0];
#pragma unroll
      for (int nf = 0; nf < 4; ++nf)
#pragma unroll
        for (int r = 0; r < 4; ++r) mt = fmaxf(mt, s[nf][r]);
      mt = fmaxf(mt, __shfl_xor(mt, 16));
      mt = fmaxf(mt, __shfl_xor(mt, 32));
      float mn = fmaxf(mr, mt);
      float fr = exp2f(mr - mn);
      mr = mn;
      float ps = 0.f;
#pragma unroll
      for (int nf = 0; nf < 4; ++nf)
#pragma unroll
        for (int r = 0; r < 4; ++r) {
          float p = exp2f(s[nf][r] - mn);
          s[nf][r] = p; ps += p;
        }
      ps += __shfl_xor(ps, 16);
      ps += __shfl_xor(ps, 32);
      lr = lr * fr + ps;
#pragma unroll
      for (int dt = 0; dt < 4; ++dt) o[dt] *= fr;

      // pack P to bf16 pairs: w0[nf] = (p[0],p[1]), w1[nf] = (p[2],p[3])
      unsigned w0[4], w1[4];
#pragma unroll
      for (int nf = 0; nf < 4; ++nf) {
        w0[nf] = cvt_pk_bf16(s[nf][0], s[nf][1]);
        w1[nf] = cvt_pk_bf16(s[nf][2], s[nf][3]);
      }

      // PV per 32-kv slice: form B-frag of P^T (lane-uniform shfl + dest-side select)
#pragma unroll
      for (int ks = 0; ks < 2; ++ks) {
        int a0 = __shfl((int)w0[2 * ks],     src0);
        int a1 = __shfl((int)w0[2 * ks + 1], src0);
        int b0 = __shfl((int)w1[2 * ks],     src0);
        int b1 = __shfl((int)w1[2 * ks + 1], src0);
        int c0 = __shfl((int)w0[2 * ks],     src1);
        int c1 = __shfl((int)w0[2 * ks + 1], src1);
        int d0 = __shfl((int)w1[2 * ks],     src1);
        int d1 = __shfl((int)w1[2 * ks + 1], src1);
        union { int i[4]; s16x8 v; } pu;
        pu.i[0] = hi_nf ? a1 : a0;
        pu.i[1] = hi_nf ? b1 : b0;
        pu.i[2] = hi_nf ? c1 : c0;
        pu.i[3] = hi_nf ? d1 : d0;
#pragma unroll
        for (int dt = 0; dt < 4; ++dt)
          o[dt] = mfma16(vf[ks][dt], pu.v, o[dt]);
      }
    }

    const float inv = 1.0f / lr;
    const size_t obase = (size_t)(b * L_SEQ + qi) * CDIM + h * HD + lg * 4;
#pragma unroll
    for (int dt = 0; dt < 4; ++dt) {
      f32x4 ov = o[dt] * inv;
      *(f32x4*)(out + obase + dt * 16) = ov;
    }
  }
}

extern "C" void kernel_launch(void* const* d_in, const int* in_sizes, int n_in,
                              void* d_out, int out_size, void* d_ws, size_t ws_size,
                              hipStream_t stream) {
  const float* x    = (const float*)d_in[0];
  const float* W    = (const float*)d_in[1];
  const float* bqkv = (const float*)d_in[2];
  float* out = (float*)d_out;
  char* ws = (char*)d_ws;

  const size_t SZ_XB  = (size_t)8192 * 1024 * 2;   // 16,777,216
  const size_t SZ_WT  = (size_t)3072 * 1024 * 2;   //  6,291,456
  const size_t SZ_HEAD = (size_t)NBH * L_SEQ * HD * 2; // 16,777,216

  short* xb  = (short*)ws;                                  // dead after gemm
  short* wtb = (short*)(ws + SZ_XB);
  short* Qo  = (short*)(ws + SZ_XB + SZ_WT);
  short* Ko  = (short*)(ws + SZ_XB + SZ_WT + SZ_HEAD);
  short* Vo  = (short*)(ws + SZ_XB + SZ_WT + 2 * SZ_HEAD);
  short* Vtb = (short*)ws;                                  // aliases xb (safe: used after gemm)

  convert_f32_bf16<<<8192, 256, 0, stream>>>(x, xb);
  transpose_w<<<dim3(48, 16), 256, 0, stream>>>(W, wtb);
  qkv_gemm<<<dim3(64, 24), 256, 0, stream>>>(xb, wtb, bqkv, Qo, Ko, Vo);
  transpose_v<<<dim3(32, 64), 256, 0, stream>>>(Vo, Vtb);
  attn<<<dim3(16, 64), 256, 0, stream>>>(Qo, Ko, Vtb, out);
}